// Round 1
// baseline (27.798 us; speedup 1.0000x reference)
//
#include <hip/hip_runtime.h>

// Triple-pendulum Hamiltonian dynamics, closed form.
// Input y[N][6] = (th1,th2,th3,p1,p2,p3); output (dth, dp/dt).
// M = [[3, 2c12, c13],[2c12, 2, c23],[c13, c23, 1]], cij = cos(thi-thj)
// dth = adj(M) p / det(M)
// dp1 = -2 dth1 dth2 s12 - dth1 dth3 s13 - 3 G sin th1
// dp2 =  2 dth1 dth2 s12 - dth2 dth3 s23 - 2 G sin th2
// dp3 =      dth1 dth3 s13 + dth2 dth3 s23 -  G sin th3

#define GACC 9.81f

__device__ __forceinline__ void dyn6(float th1, float th2, float th3,
                                     float p1, float p2, float p3,
                                     float* __restrict__ o) {
    float s1, c1, s2, c2, s3, c3;
    __sincosf(th1, &s1, &c1);
    __sincosf(th2, &s2, &c2);
    __sincosf(th3, &s3, &c3);
    // angle differences via products (no extra trig)
    float c12 = c1 * c2 + s1 * s2, s12 = s1 * c2 - c1 * s2;
    float c13 = c1 * c3 + s1 * s3, s13 = s1 * c3 - c1 * s3;
    float c23 = c2 * c3 + s2 * s3, s23 = s2 * c3 - c2 * s3;
    // adjugate (symmetric) of M
    float A11 = 2.0f - c23 * c23;
    float A12 = c23 * c13 - 2.0f * c12;
    float A13 = 2.0f * (c12 * c23 - c13);
    float A22 = 3.0f - c13 * c13;
    float A23 = 2.0f * c12 * c13 - 3.0f * c23;
    float A33 = 6.0f - 4.0f * c12 * c12;
    float det = 3.0f * A11 + 2.0f * c12 * A12 + c13 * A13;
    float inv = 1.0f / det;
    float dth1 = (A11 * p1 + A12 * p2 + A13 * p3) * inv;
    float dth2 = (A12 * p1 + A22 * p2 + A23 * p3) * inv;
    float dth3 = (A13 * p1 + A23 * p2 + A33 * p3) * inv;
    o[0] = dth1;
    o[1] = dth2;
    o[2] = dth3;
    float t12 = dth1 * dth2 * s12;
    float t13 = dth1 * dth3 * s13;
    float t23 = dth2 * dth3 * s23;
    o[3] = -2.0f * t12 - t13 - 3.0f * GACC * s1;
    o[4] =  2.0f * t12 - t23 - 2.0f * GACC * s2;
    o[5] =  t13 + t23 - GACC * s3;
}

// One thread handles 2 rows = 48 bytes = three 16B-aligned float4s.
__global__ __launch_bounds__(256) void pend3_kernel(const float* __restrict__ y,
                                                    float* __restrict__ out,
                                                    int nPairs) {
    int idx = blockIdx.x * blockDim.x + threadIdx.x;
    if (idx >= nPairs) return;

    const float4* __restrict__ yin = reinterpret_cast<const float4*>(y) + (size_t)idx * 3;
    float4 a = yin[0];
    float4 b = yin[1];
    float4 c = yin[2];

    float o0[6], o1[6];
    // row 0: a.x a.y a.z a.w b.x b.y
    dyn6(a.x, a.y, a.z, a.w, b.x, b.y, o0);
    // row 1: b.z b.w c.x c.y c.z c.w
    dyn6(b.z, b.w, c.x, c.y, c.z, c.w, o1);

    float4 oa = make_float4(o0[0], o0[1], o0[2], o0[3]);
    float4 ob = make_float4(o0[4], o0[5], o1[0], o1[1]);
    float4 oc = make_float4(o1[2], o1[3], o1[4], o1[5]);

    float4* __restrict__ oo = reinterpret_cast<float4*>(out) + (size_t)idx * 3;
    oo[0] = oa;
    oo[1] = ob;
    oo[2] = oc;
}

extern "C" void kernel_launch(void* const* d_in, const int* in_sizes, int n_in,
                              void* d_out, int out_size, void* d_ws, size_t ws_size,
                              hipStream_t stream) {
    // d_in[0] = t (unused, 1 float), d_in[1] = y (N*6 floats)
    const float* y = (const float*)d_in[1];
    float* out = (float*)d_out;
    int n_rows = in_sizes[1] / 6;          // 2097152
    int nPairs = n_rows / 2;               // 1048576 (N is even)
    int block = 256;
    int grid = (nPairs + block - 1) / block;
    pend3_kernel<<<grid, block, 0, stream>>>(y, out, nPairs);
}

// Round 2
// 20.856 us; speedup vs baseline: 1.3328x; 1.3328x over previous
//
#include <hip/hip_runtime.h>

// Triple-pendulum Hamiltonian dynamics, closed form.
// Input y[N][6] = (th1,th2,th3,p1,p2,p3); output (dth, dp/dt).
// M = [[3, 2c12, c13],[2c12, 2, c23],[c13, c23, 1]], cij = cos(thi-thj)
// dth = adj(M) p / det(M)
// dp1 = -2 dth1 dth2 s12 - dth1 dth3 s13 - 3 G sin th1
// dp2 =  2 dth1 dth2 s12 - dth2 dth3 s23 - 2 G sin th2
// dp3 =      dth1 dth3 s13 + dth2 dth3 s23 -  G sin th3
//
// Memory layout strategy: all GLOBAL accesses are unit-stride float4
// (lane i <-> base+i). AoS rows (48B/thread) are picked apart via LDS.
// LDS float4 index is XOR-swizzled (j ^= (j>>3)&3) so the 48B-stride
// read side is <=2-way bank aliased (free) instead of 8-way.

#define GACC 9.81f

__device__ __forceinline__ void dyn6(float th1, float th2, float th3,
                                     float p1, float p2, float p3,
                                     float* __restrict__ o) {
    float s1, c1, s2, c2, s3, c3;
    __sincosf(th1, &s1, &c1);
    __sincosf(th2, &s2, &c2);
    __sincosf(th3, &s3, &c3);
    // angle differences via products (no extra trig)
    float c12 = c1 * c2 + s1 * s2, s12 = s1 * c2 - c1 * s2;
    float c13 = c1 * c3 + s1 * s3, s13 = s1 * c3 - c1 * s3;
    float c23 = c2 * c3 + s2 * s3, s23 = s2 * c3 - c2 * s3;
    // adjugate (symmetric) of M
    float A11 = 2.0f - c23 * c23;
    float A12 = c23 * c13 - 2.0f * c12;
    float A13 = 2.0f * (c12 * c23 - c13);
    float A22 = 3.0f - c13 * c13;
    float A23 = 2.0f * c12 * c13 - 3.0f * c23;
    float A33 = 6.0f - 4.0f * c12 * c12;
    float det = 3.0f * A11 + 2.0f * c12 * A12 + c13 * A13;
    float inv = 1.0f / det;
    float dth1 = (A11 * p1 + A12 * p2 + A13 * p3) * inv;
    float dth2 = (A12 * p1 + A22 * p2 + A23 * p3) * inv;
    float dth3 = (A13 * p1 + A23 * p2 + A33 * p3) * inv;
    o[0] = dth1;
    o[1] = dth2;
    o[2] = dth3;
    float t12 = dth1 * dth2 * s12;
    float t13 = dth1 * dth3 * s13;
    float t23 = dth2 * dth3 * s23;
    o[3] = -2.0f * t12 - t13 - 3.0f * GACC * s1;
    o[4] =  2.0f * t12 - t23 - 2.0f * GACC * s2;
    o[5] =  t13 + t23 - GACC * s3;
}

__device__ __forceinline__ int swz(int j) { return j ^ ((j >> 3) & 3); }

// Block = 256 threads, 512 rows/block, 768 float4 in + 768 float4 out.
__global__ __launch_bounds__(256) void pend3_kernel(const float4* __restrict__ y4,
                                                    float4* __restrict__ out4) {
    __shared__ float4 sIn[768];
    __shared__ float4 sOut[768];
    const int tid = threadIdx.x;
    const size_t base = (size_t)blockIdx.x * 768;

    // Global -> LDS, unit-stride (16B/lane), swizzled dest (conflict-free:
    // XOR permutes within each 8-slot group a wave's 8-lane cluster writes).
#pragma unroll
    for (int k = 0; k < 3; ++k) {
        int j = tid + k * 256;
        sIn[swz(j)] = y4[base + j];
    }
    __syncthreads();

    // Each thread picks up its 2 rows (3 float4 at 48B stride, swizzled read
    // -> <=2-way bank alias, free).
    const int j0 = 3 * tid;
    float4 a = sIn[swz(j0)];
    float4 b = sIn[swz(j0 + 1)];
    float4 c = sIn[swz(j0 + 2)];

    float o0[6], o1[6];
    dyn6(a.x, a.y, a.z, a.w, b.x, b.y, o0);
    dyn6(b.z, b.w, c.x, c.y, c.z, c.w, o1);

    sOut[swz(j0)]     = make_float4(o0[0], o0[1], o0[2], o0[3]);
    sOut[swz(j0 + 1)] = make_float4(o0[4], o0[5], o1[0], o1[1]);
    sOut[swz(j0 + 2)] = make_float4(o1[2], o1[3], o1[4], o1[5]);
    __syncthreads();

    // LDS -> global, unit-stride.
#pragma unroll
    for (int k = 0; k < 3; ++k) {
        int j = tid + k * 256;
        out4[base + j] = sOut[swz(j)];
    }
}

extern "C" void kernel_launch(void* const* d_in, const int* in_sizes, int n_in,
                              void* d_out, int out_size, void* d_ws, size_t ws_size,
                              hipStream_t stream) {
    // d_in[0] = t (unused, 1 float), d_in[1] = y (N*6 floats)
    const float4* y4 = (const float4*)d_in[1];
    float4* out4 = (float4*)d_out;
    int nQuads = in_sizes[1] / 4;      // 3145728 for N=2097152 rows
    int grid = nQuads / 768;           // 4096 full blocks (exact: 768*4096)
    pend3_kernel<<<grid, 256, 0, stream>>>(y4, out4);
}

// Round 4
// 20.818 us; speedup vs baseline: 1.3353x; 1.0018x over previous
//
#include <hip/hip_runtime.h>

// Triple-pendulum Hamiltonian dynamics, closed form.
// Input y[N][6] = (th1,th2,th3,p1,p2,p3); output (dth, dp/dt).
// M = [[3, 2c12, c13],[2c12, 2, c23],[c13, c23, 1]], cij = cos(thi-thj)
// dth = adj(M) p / det(M)
// dp1 = -2 dth1 dth2 s12 - dth1 dth3 s13 - 3 G sin th1
// dp2 =  2 dth1 dth2 s12 - dth2 dth3 s23 - 2 G sin th2
// dp3 =      dth1 dth3 s13 + dth2 dth3 s23 -  G sin th3
//
// Structure: wave-synchronous AoS<->SoA through LDS. Each wave owns a
// private 192-float4 (3KB) quarter of one shared buffer, so ALL cross-lane
// LDS traffic is intra-wave: no __syncthreads anywhere. DS ops complete
// in-order per wave (HW); wavefront-scope fences (zero instructions) pin
// compiler ordering at the cross-lane phase boundaries.
// Stride-3 float4 LDS reads are bank-conflict-free (odd stride: starts
// 12l mod 32 cover all 32 banks disjointly per 8 lanes) -> no swizzle.
// Global traffic is pure unit-stride 16B; stores are nontemporal
// (output never re-read -> skip write-allocate/dirty-linger in L2/L3).
// Native ext_vector f32x4 (not HIP float4 class) so
// __builtin_nontemporal_store accepts the pointer.

#define GACC 9.81f

typedef float f32x4 __attribute__((ext_vector_type(4)));

__device__ __forceinline__ void dyn6(float th1, float th2, float th3,
                                     float p1, float p2, float p3,
                                     float* __restrict__ o) {
    float s1, c1, s2, c2, s3, c3;
    __sincosf(th1, &s1, &c1);
    __sincosf(th2, &s2, &c2);
    __sincosf(th3, &s3, &c3);
    // angle differences via products (no extra trig)
    float c12 = c1 * c2 + s1 * s2, s12 = s1 * c2 - c1 * s2;
    float c13 = c1 * c3 + s1 * s3, s13 = s1 * c3 - c1 * s3;
    float c23 = c2 * c3 + s2 * s3, s23 = s2 * c3 - c2 * s3;
    // adjugate (symmetric) of M
    float A11 = 2.0f - c23 * c23;
    float A12 = c23 * c13 - 2.0f * c12;
    float A13 = 2.0f * (c12 * c23 - c13);
    float A22 = 3.0f - c13 * c13;
    float A23 = 2.0f * c12 * c13 - 3.0f * c23;
    float A33 = 6.0f - 4.0f * c12 * c12;
    float det = 3.0f * A11 + 2.0f * c12 * A12 + c13 * A13;
    float inv = 1.0f / det;
    float dth1 = (A11 * p1 + A12 * p2 + A13 * p3) * inv;
    float dth2 = (A12 * p1 + A22 * p2 + A23 * p3) * inv;
    float dth3 = (A13 * p1 + A23 * p2 + A33 * p3) * inv;
    o[0] = dth1;
    o[1] = dth2;
    o[2] = dth3;
    float t12 = dth1 * dth2 * s12;
    float t13 = dth1 * dth3 * s13;
    float t23 = dth2 * dth3 * s23;
    o[3] = -2.0f * t12 - t13 - 3.0f * GACC * s1;
    o[4] =  2.0f * t12 - t23 - 2.0f * GACC * s2;
    o[5] =  t13 + t23 - GACC * s3;
}

#define WFENCE() __builtin_amdgcn_fence(__ATOMIC_SEQ_CST, "wavefront")

// 256 threads = 4 waves; each wave: 192 float4 = 128 rows per tile.
// Tile = 768 float4 = 512 rows. Grid-stride over tiles.
__global__ __launch_bounds__(256, 6) void pend3_kernel(const f32x4* __restrict__ y4,
                                                       f32x4* __restrict__ out4,
                                                       int nTiles) {
    __shared__ f32x4 s[768];            // 12KB; wave w owns s[192w .. 192w+191]
    const int wave = threadIdx.x >> 6;
    const int lane = threadIdx.x & 63;
    f32x4* sw = s + wave * 192;

    for (int tile = blockIdx.x; tile < nTiles; tile += gridDim.x) {
        const size_t gbase = (size_t)tile * 768 + wave * 192;

        // stage in: unit-stride global -> LDS (intra-wave quarter)
#pragma unroll
        for (int k = 0; k < 3; ++k)
            sw[lane + 64 * k] = y4[gbase + lane + 64 * k];
        WFENCE();   // cross-lane boundary: stage-write -> strided read

        // each lane picks up its 2 rows (stride-3 float4, conflict-free)
        const int j0 = 3 * lane;
        f32x4 a = sw[j0];
        f32x4 b = sw[j0 + 1];
        f32x4 c = sw[j0 + 2];

        float o0[6], o1[6];
        dyn6(a.x, a.y, a.z, a.w, b.x, b.y, o0);
        dyn6(b.z, b.w, c.x, c.y, c.z, c.w, o1);

        // overwrite own slots with results (same-lane same-address: no hazard)
        f32x4 r0 = {o0[0], o0[1], o0[2], o0[3]};
        f32x4 r1 = {o0[4], o0[5], o1[0], o1[1]};
        f32x4 r2 = {o1[2], o1[3], o1[4], o1[5]};
        sw[j0]     = r0;
        sw[j0 + 1] = r1;
        sw[j0 + 2] = r2;
        WFENCE();   // cross-lane boundary: strided result-write -> linear read

        // stream out: LDS -> global, unit-stride, nontemporal
#pragma unroll
        for (int k = 0; k < 3; ++k) {
            f32x4 v = sw[lane + 64 * k];
            __builtin_nontemporal_store(v, &out4[gbase + lane + 64 * k]);
        }
        WFENCE();   // next tile's stage-in overwrites (same-lane addresses, but pin order)
    }
}

extern "C" void kernel_launch(void* const* d_in, const int* in_sizes, int n_in,
                              void* d_out, int out_size, void* d_ws, size_t ws_size,
                              hipStream_t stream) {
    // d_in[0] = t (unused, 1 float), d_in[1] = y (N*6 floats)
    const f32x4* y4 = (const f32x4*)d_in[1];
    f32x4* out4 = (f32x4*)d_out;
    int nQuads = in_sizes[1] / 4;          // 3145728
    int nTiles = nQuads / 768;             // 4096 (exact)
    int grid = nTiles < 2048 ? nTiles : 2048;  // 8 blocks/CU, 2 tiles each
    pend3_kernel<<<grid, 256, 0, stream>>>(y4, out4, nTiles);
}